// Round 4
// baseline (279.592 us; speedup 1.0000x reference)
//
#include <hip/hip_runtime.h>
#include <hip/hip_bf16.h>

typedef unsigned short ushort_t;
typedef __attribute__((ext_vector_type(8))) short s16x8;   // 8 bf16 (4 VGPRs)
typedef __attribute__((ext_vector_type(4))) float f32x4;
typedef __attribute__((ext_vector_type(16))) float f32x16;
typedef __attribute__((ext_vector_type(4))) unsigned int u32x4;

#define EMB 768
#define HEADS 12
#define DH 64
#define BATCH 4
#define SEQ 2048
#define MTOK (BATCH*SEQ)     // 8192
#define NQKV (3*EMB)         // 2304
#define LOG2E 1.44269504088896f

__device__ __forceinline__ ushort_t f2bf(float f) {
  unsigned u = __float_as_uint(f);
  u += 0x7fffu + ((u >> 16) & 1u);   // RNE; inputs have no NaN/Inf
  return (ushort_t)(u >> 16);
}
__device__ __forceinline__ unsigned pk2bf(float a, float b) {
  return (unsigned)f2bf(a) | ((unsigned)f2bf(b) << 16);
}

__device__ __forceinline__ void gload_lds16(const void* g, void* l) {
  __builtin_amdgcn_global_load_lds(
      (const __attribute__((address_space(1))) unsigned*)g,
      (__attribute__((address_space(3))) unsigned*)l, 16, 0, 0);
}

// ---------------- fp32 -> bf16 convert (vectorized float4 -> 4x bf16) ----------------
__global__ void cvt_bf16(const float* __restrict__ in, ushort_t* __restrict__ out, int n4) {
  int i = blockIdx.x * blockDim.x + threadIdx.x;
  if (i >= n4) return;
  const float4 v = reinterpret_cast<const float4*>(in)[i];
  reinterpret_cast<uint2*>(out)[i] = make_uint2(pk2bf(v.x, v.y), pk2bf(v.z, v.w));
}

// ---------------- GEMM: C[M,N] = A[M,K] @ BT[N,K]^T + bias ----------------
// MODE 0: fp32 out to Cf.  MODE 1: scatter bf16 into Q[bh,n,d] (pre-scaled by log2e),
//         K[bh,n,d], Vt[bh,d,pos(n)] where pos(n) swaps bits 2<->3 of (n&31)
//         (matches the 32x32 MFMA C-layout key order so attn reads are contiguous).
#define TM 128
#define TN 128
#define BKG 64

template<int MODE>
__global__ __launch_bounds__(256, 2) void gemm_bt(
    const ushort_t* __restrict__ A, const ushort_t* __restrict__ BT,
    const float* __restrict__ bias, float* __restrict__ Cf,
    ushort_t* __restrict__ Qd, ushort_t* __restrict__ Kd, ushort_t* __restrict__ Vt,
    int M, int N, int K)
{
  __shared__ alignas(16) ushort_t As[TM*BKG];   // [128][64] bf16, XOR-swizzled (row&7)<<4
  __shared__ alignas(16) ushort_t Bs[TN*BKG];
  const int t = threadIdx.x;
  const int w = t >> 6, l = t & 63, g = l >> 4, r = l & 15;
  const int wr = w >> 1, wc = w & 1;                 // 2x2 wave grid, 64x64 per wave
  const int m0 = blockIdx.y * TM, n0 = blockIdx.x * TN;

  f32x4 acc[4][4] = {};

  for (int kt = 0; kt < K; kt += BKG) {
    // stage: linear LDS dest + inverse-swizzled global source (both-sides-or-neither)
#pragma unroll
    for (int p = 0; p < 4; ++p) {
      const int off = (t + p*256) * 16;              // byte in 16KB tile
      const int row = off >> 7;                      // 128B per row
      const int scb = (off & 127) ^ ((row & 7) << 4);
      gload_lds16(A  + (size_t)(m0+row)*K + kt + (scb>>1), (char*)As + off);
      gload_lds16(BT + (size_t)(n0+row)*K + kt + (scb>>1), (char*)Bs + off);
    }
    __syncthreads();   // compiler drains vmcnt(0) before s_barrier

    s16x8 fa[4][2], fb[4][2];
#pragma unroll
    for (int mi = 0; mi < 4; ++mi)
#pragma unroll
      for (int kk = 0; kk < 2; ++kk) {
        const int ra = wr*64 + mi*16 + r;
        fa[mi][kk] = *(const s16x8*)((const char*)As + ra*128 + ((g*16 + kk*64) ^ ((ra&7)<<4)));
        const int rb = wc*64 + mi*16 + r;
        fb[mi][kk] = *(const s16x8*)((const char*)Bs + rb*128 + ((g*16 + kk*64) ^ ((rb&7)<<4)));
      }
#pragma unroll
    for (int mi = 0; mi < 4; ++mi)
#pragma unroll
      for (int ni = 0; ni < 4; ++ni) {
        acc[mi][ni] = __builtin_amdgcn_mfma_f32_16x16x32_bf16(fa[mi][0], fb[ni][0], acc[mi][ni], 0,0,0);
        acc[mi][ni] = __builtin_amdgcn_mfma_f32_16x16x32_bf16(fa[mi][1], fb[ni][1], acc[mi][ni], 0,0,0);
      }
    __syncthreads();
  }

  // epilogue: C/D layout col = lane&15, row = (lane>>4)*4 + reg
#pragma unroll
  for (int mi = 0; mi < 4; ++mi)
#pragma unroll
    for (int ni = 0; ni < 4; ++ni) {
      const int col = n0 + wc*64 + ni*16 + r;
      const float bv = bias[col];
#pragma unroll
      for (int q = 0; q < 4; ++q) {
        const int rowg = m0 + wr*64 + mi*16 + g*4 + q;
        const float v = acc[mi][ni][q] + bv;
        if (MODE == 0) {
          Cf[(size_t)rowg * N + col] = v;
        } else {
          // col in [0,2304): (h:12, d:64, which:3), which fastest
          const int h = col / 192;
          const int rem = col - h*192;
          const int d = rem / 3;
          const int which = rem - d*3;
          const int bb = rowg >> 11, nn = rowg & 2047;
          if (which == 2) {
            // store V^T with bit2<->bit3-swapped column order within each 32-token block
            const int np = (nn & ~12) | ((nn & 4) << 1) | ((nn & 8) >> 1);
            Vt[((size_t)(bb*HEADS + h)*DH + d)*SEQ + np] = f2bf(v);
          } else {
            const size_t idx = ((size_t)(bb*HEADS + h)*SEQ + nn)*DH + d;
            if (which == 0) Qd[idx] = f2bf(v * LOG2E);   // fold log2(e) into Q
            else            Kd[idx] = f2bf(v);
          }
        }
      }
    }
}

// ---------------- flash attention: 32x32 MFMA, LDS-free, L2-resident K/V ----------------
// Per wave: 32 q rows, sweep all 2048 keys in 32-key groups.
// S^T = K @ Q^T; P stays lane-local (C-layout key list == stored V column order, by the
// bit2<->3 permutation of Vt) so the PV B-frag is just pk2bf pairs and the PV A-frag is
// one contiguous 16B load. No LDS, no barriers, no cross-lane ops in the loop.
__global__ __launch_bounds__(256, 3) void attn_fwd(
    const ushort_t* __restrict__ Qd, const ushort_t* __restrict__ Kd,
    const ushort_t* __restrict__ Vt, ushort_t* __restrict__ Oa)
{
  const int t = threadIdx.x;
  const int w = t >> 6, l = t & 63;
  const int c31 = l & 31, hi = l >> 5;
  // XCD-chunked swizzle: 768 blocks = 8 XCDs * 96; XCD k gets logical [96k, 96k+96) = 6 bh
  const int blk = blockIdx.x;
  const int logical = (blk & 7) * 96 + (blk >> 3);
  const int bh = logical >> 4;
  const int qt = logical & 15;
  const int q0 = qt * 128 + w * 32;
  const int b = bh / HEADS, h = bh - b * HEADS;

  const ushort_t* Qp = Qd + (size_t)bh * SEQ * DH;
  const ushort_t* Kp = Kd + (size_t)bh * SEQ * DH;
  const ushort_t* Vp = Vt + (size_t)bh * DH * SEQ;

  // Q B-frags (resident): chunk c -> Q[q0 + (l&31)][16c + 8hi + 0..7]  (pre-scaled by log2e)
  s16x8 qf[4];
  {
    const ushort_t* qp = Qp + (size_t)(q0 + c31) * DH + hi * 8;
#pragma unroll
    for (int c = 0; c < 4; ++c) qf[c] = *(const s16x8*)(qp + c * 16);
  }

  f32x16 oacc0 = {}, oacc1 = {};   // O^T d-frags 0..31, 32..63; col q = l&31
  float psum = 0.f;

  const ushort_t* kp  = Kp + (size_t)c31 * DH + hi * 8;    // advances 32 keys/group
  const ushort_t* vp0 = Vp + (size_t)c31 * SEQ + hi * 8;   // V^T rows d=0..31 (permuted cols)
  const ushort_t* vp1 = vp0 + (size_t)32 * SEQ;            // rows d=32..63

  for (int g = 0; g < SEQ / 32; ++g) {
    // K A-frags: K[32g + (l&31)][16c + 8hi + 0..7] -- contiguous 16B
    s16x8 kf0 = *(const s16x8*)(kp);
    s16x8 kf1 = *(const s16x8*)(kp + 16);
    s16x8 kf2 = *(const s16x8*)(kp + 32);
    s16x8 kf3 = *(const s16x8*)(kp + 48);
    // V A-frags at permuted columns: element e of lane (hi) = the key this lane's
    // C-layout row list gives -- stored contiguously at pos 32g + 16*frag + 8*hi
    s16x8 va00 = *(const s16x8*)(vp0);          // frag0, d=0..31
    s16x8 va01 = *(const s16x8*)(vp0 + 16);     // frag1, d=0..31
    s16x8 va10 = *(const s16x8*)(vp1);          // frag0, d=32..63
    s16x8 va11 = *(const s16x8*)(vp1 + 16);     // frag1, d=32..63

    // S^T[key][q] = K @ Q^T
    f32x16 s = {};
    s = __builtin_amdgcn_mfma_f32_32x32x16_bf16(kf0, qf[0], s, 0, 0, 0);
    s = __builtin_amdgcn_mfma_f32_32x32x16_bf16(kf1, qf[1], s, 0, 0, 0);
    s = __builtin_amdgcn_mfma_f32_32x32x16_bf16(kf2, qf[2], s, 0, 0, 0);
    s = __builtin_amdgcn_mfma_f32_32x32x16_bf16(kf3, qf[3], s, 0, 0, 0);

    // P = 2^S (fixed max=0, exact). Lane's C-layout rows: key = (r2&3)+8*(r2>>2)+4*hi.
    float pe[16];
#pragma unroll
    for (int r2 = 0; r2 < 16; ++r2) {
      pe[r2] = __builtin_amdgcn_exp2f(s[r2]);
      psum += pe[r2];
    }
    // PV B-frags: natural pe order (keys match stored V column order by construction)
    u32x4 f0u = { pk2bf(pe[0],  pe[1]),  pk2bf(pe[2],  pe[3]),
                  pk2bf(pe[4],  pe[5]),  pk2bf(pe[6],  pe[7]) };
    u32x4 f1u = { pk2bf(pe[8],  pe[9]),  pk2bf(pe[10], pe[11]),
                  pk2bf(pe[12], pe[13]), pk2bf(pe[14], pe[15]) };
    const s16x8 pf0 = __builtin_bit_cast(s16x8, f0u);
    const s16x8 pf1 = __builtin_bit_cast(s16x8, f1u);

    // O^T += V^T @ P^T
    oacc0 = __builtin_amdgcn_mfma_f32_32x32x16_bf16(va00, pf0, oacc0, 0, 0, 0);
    oacc0 = __builtin_amdgcn_mfma_f32_32x32x16_bf16(va01, pf1, oacc0, 0, 0, 0);
    oacc1 = __builtin_amdgcn_mfma_f32_32x32x16_bf16(va10, pf0, oacc1, 0, 0, 0);
    oacc1 = __builtin_amdgcn_mfma_f32_32x32x16_bf16(va11, pf1, oacc1, 0, 0, 0);

    kp  += 32 * DH;
    vp0 += 32;
    vp1 += 32;
  }

  // row sum: lane l holds 16 of each 32-key group for q=l&31; lane l^32 has the rest
  float lt = psum + __shfl_xor(psum, 32);
  const float scale = 0.036084391824351615f / lt;   // (1/sqrt(768)) / l

  ushort_t* op = Oa + ((size_t)(b * SEQ + q0 + c31)) * EMB + h * DH;
  auto emit = [&](const f32x16& o, int f) {
#pragma unroll
    for (int rq = 0; rq < 4; ++rq) {
      const int dbase = f * 32 + 8 * rq + 4 * hi;    // d = dbase + (reg&3)
      unsigned w0 = pk2bf(o[rq*4+0] * scale, o[rq*4+1] * scale);
      unsigned w1 = pk2bf(o[rq*4+2] * scale, o[rq*4+3] * scale);
      *reinterpret_cast<unsigned*>(op + dbase)     = w0;
      *reinterpret_cast<unsigned*>(op + dbase + 2) = w1;
    }
  };
  emit(oacc0, 0);
  emit(oacc1, 1);
}

// ---------------- host launch ----------------
extern "C" void kernel_launch(void* const* d_in, const int* in_sizes, int n_in,
                              void* d_out, int out_size, void* d_ws, size_t ws_size,
                              hipStream_t stream) {
  const float* x      = (const float*)d_in[0];
  const float* qkv_w  = (const float*)d_in[1];
  const float* qkv_b  = (const float*)d_in[2];
  const float* proj_w = (const float*)d_in[3];
  const float* proj_b = (const float*)d_in[4];
  float* out = (float*)d_out;

  ushort_t* xb    = (ushort_t*)d_ws;
  ushort_t* wqkv  = xb    + (size_t)MTOK*EMB;
  ushort_t* wproj = wqkv  + (size_t)NQKV*EMB;
  ushort_t* Qd    = wproj + (size_t)EMB*EMB;
  ushort_t* Kd    = Qd    + (size_t)MTOK*EMB;
  ushort_t* Vt    = Kd    + (size_t)MTOK*EMB;
  ushort_t* Oa    = Vt    + (size_t)MTOK*EMB;

  {
    int n4 = MTOK*EMB/4;
    cvt_bf16<<<(n4+255)/256, 256, 0, stream>>>(x, xb, n4);
  }
  {
    int n4 = NQKV*EMB/4;
    cvt_bf16<<<(n4+255)/256, 256, 0, stream>>>(qkv_w, wqkv, n4);
  }
  {
    int n4 = EMB*EMB/4;
    cvt_bf16<<<(n4+255)/256, 256, 0, stream>>>(proj_w, wproj, n4);
  }

  gemm_bt<1><<<dim3(NQKV/TN, MTOK/TM), 256, 0, stream>>>(
      xb, wqkv, qkv_b, nullptr, Qd, Kd, Vt, MTOK, NQKV, EMB);

  attn_fwd<<<768, 256, 0, stream>>>(Qd, Kd, Vt, Oa);

  gemm_bt<0><<<dim3(EMB/TN, MTOK/TM), 256, 0, stream>>>(
      Oa, wproj, proj_b, out, nullptr, nullptr, nullptr, MTOK, EMB, EMB);
}

// Round 5
// 179.932 us; speedup vs baseline: 1.5539x; 1.5539x over previous
//
#include <hip/hip_runtime.h>
#include <hip/hip_bf16.h>

typedef unsigned short ushort_t;
typedef __attribute__((ext_vector_type(8))) short s16x8;   // 8 bf16 (4 VGPRs)
typedef __attribute__((ext_vector_type(4))) float f32x4;
typedef __attribute__((ext_vector_type(16))) float f32x16;
typedef __attribute__((ext_vector_type(4))) unsigned int u32x4;

#define EMB 768
#define HEADS 12
#define DH 64
#define BATCH 4
#define SEQ 2048
#define MTOK (BATCH*SEQ)     // 8192
#define NQKV (3*EMB)         // 2304
#define LOG2E 1.44269504088896f

__device__ __forceinline__ ushort_t f2bf(float f) {
  unsigned u = __float_as_uint(f);
  u += 0x7fffu + ((u >> 16) & 1u);   // RNE; inputs have no NaN/Inf
  return (ushort_t)(u >> 16);
}
__device__ __forceinline__ unsigned pk2bf(float a, float b) {
  return (unsigned)f2bf(a) | ((unsigned)f2bf(b) << 16);
}

__device__ __forceinline__ void gload_lds16(const void* g, void* l) {
  __builtin_amdgcn_global_load_lds(
      (const __attribute__((address_space(1))) unsigned*)g,
      (__attribute__((address_space(3))) unsigned*)l, 16, 0, 0);
}

// ---------------- fp32 -> bf16 convert (vectorized float4 -> 4x bf16) ----------------
__global__ void cvt_bf16(const float* __restrict__ in, ushort_t* __restrict__ out, int n4) {
  int i = blockIdx.x * blockDim.x + threadIdx.x;
  if (i >= n4) return;
  const float4 v = reinterpret_cast<const float4*>(in)[i];
  reinterpret_cast<uint2*>(out)[i] = make_uint2(pk2bf(v.x, v.y), pk2bf(v.z, v.w));
}

// ---------------- GEMM: C[M,N] = A[M,K] @ BT[N,K]^T + bias ----------------
// MODE 0: fp32 out to Cf.  MODE 1: scatter bf16 into Q[bh,n,d] (pre-scaled by log2e),
//         K[bh,n,d], Vt[bh,d,pos(n)] where pos(n) swaps bits 2<->3 of (n&31)
//         (matches the 32x32 MFMA C-layout key order so attn reads are contiguous).
#define TM 128
#define TN 128
#define BKG 64

template<int MODE>
__global__ __launch_bounds__(256, 2) void gemm_bt(
    const ushort_t* __restrict__ A, const ushort_t* __restrict__ BT,
    const float* __restrict__ bias, float* __restrict__ Cf,
    ushort_t* __restrict__ Qd, ushort_t* __restrict__ Kd, ushort_t* __restrict__ Vt,
    int M, int N, int K)
{
  __shared__ alignas(16) ushort_t As[TM*BKG];   // [128][64] bf16, XOR-swizzled (row&7)<<4
  __shared__ alignas(16) ushort_t Bs[TN*BKG];
  const int t = threadIdx.x;
  const int w = t >> 6, l = t & 63, g = l >> 4, r = l & 15;
  const int wr = w >> 1, wc = w & 1;                 // 2x2 wave grid, 64x64 per wave
  const int m0 = blockIdx.y * TM, n0 = blockIdx.x * TN;

  f32x4 acc[4][4] = {};

  for (int kt = 0; kt < K; kt += BKG) {
    // stage: linear LDS dest + inverse-swizzled global source (both-sides-or-neither)
#pragma unroll
    for (int p = 0; p < 4; ++p) {
      const int off = (t + p*256) * 16;              // byte in 16KB tile
      const int row = off >> 7;                      // 128B per row
      const int scb = (off & 127) ^ ((row & 7) << 4);
      gload_lds16(A  + (size_t)(m0+row)*K + kt + (scb>>1), (char*)As + off);
      gload_lds16(BT + (size_t)(n0+row)*K + kt + (scb>>1), (char*)Bs + off);
    }
    __syncthreads();   // compiler drains vmcnt(0) before s_barrier

    s16x8 fa[4][2], fb[4][2];
#pragma unroll
    for (int mi = 0; mi < 4; ++mi)
#pragma unroll
      for (int kk = 0; kk < 2; ++kk) {
        const int ra = wr*64 + mi*16 + r;
        fa[mi][kk] = *(const s16x8*)((const char*)As + ra*128 + ((g*16 + kk*64) ^ ((ra&7)<<4)));
        const int rb = wc*64 + mi*16 + r;
        fb[mi][kk] = *(const s16x8*)((const char*)Bs + rb*128 + ((g*16 + kk*64) ^ ((rb&7)<<4)));
      }
#pragma unroll
    for (int mi = 0; mi < 4; ++mi)
#pragma unroll
      for (int ni = 0; ni < 4; ++ni) {
        acc[mi][ni] = __builtin_amdgcn_mfma_f32_16x16x32_bf16(fa[mi][0], fb[ni][0], acc[mi][ni], 0,0,0);
        acc[mi][ni] = __builtin_amdgcn_mfma_f32_16x16x32_bf16(fa[mi][1], fb[ni][1], acc[mi][ni], 0,0,0);
      }
    __syncthreads();
  }

  // epilogue: C/D layout col = lane&15, row = (lane>>4)*4 + reg
#pragma unroll
  for (int mi = 0; mi < 4; ++mi)
#pragma unroll
    for (int ni = 0; ni < 4; ++ni) {
      const int col = n0 + wc*64 + ni*16 + r;
      const float bv = bias[col];
#pragma unroll
      for (int q = 0; q < 4; ++q) {
        const int rowg = m0 + wr*64 + mi*16 + g*4 + q;
        const float v = acc[mi][ni][q] + bv;
        if (MODE == 0) {
          Cf[(size_t)rowg * N + col] = v;
        } else {
          // col in [0,2304): (h:12, d:64, which:3), which fastest
          const int h = col / 192;
          const int rem = col - h*192;
          const int d = rem / 3;
          const int which = rem - d*3;
          const int bb = rowg >> 11, nn = rowg & 2047;
          if (which == 2) {
            // store V^T with bit2<->bit3-swapped column order within each 32-token block
            const int np = (nn & ~12) | ((nn & 4) << 1) | ((nn & 8) >> 1);
            Vt[((size_t)(bb*HEADS + h)*DH + d)*SEQ + np] = f2bf(v);
          } else {
            const size_t idx = ((size_t)(bb*HEADS + h)*SEQ + nn)*DH + d;
            if (which == 0) Qd[idx] = f2bf(v * LOG2E);   // fold log2(e) into Q
            else            Kd[idx] = f2bf(v);
          }
        }
      }
    }
}

// ---------------- flash attention: 32x32 MFMA + LDS double-buffered K/V tiles ----------
// Per wave: 32 q rows. Per block (4 waves, 128 q rows): stage 64-key K/V tiles in LDS
// (fragment-order layout -> every ds_read_b128 is lane-contiguous, conflict-free).
// 1 barrier per tile; stage(t+1) issued before compute(t) so its latency hides.
// Softmax: fixed max=0 (exact), exp2-only, lane-local P (Vt column permutation).
#define KVT 64
#define NT (SEQ/KVT)   // 32

__global__ __launch_bounds__(256, 3) void attn_fwd(
    const ushort_t* __restrict__ Qd, const ushort_t* __restrict__ Kd,
    const ushort_t* __restrict__ Vt, ushort_t* __restrict__ Oa)
{
  // K tile: byte = dseg*1024 + key*16       (dseg = d/8, key 0..63)
  // V tile: byte = kseg*1024 + d*16         (kseg = pos/8, d 0..63)
  __shared__ alignas(16) ushort_t Ks[2][4096];
  __shared__ alignas(16) ushort_t Vs[2][4096];

  const int t = threadIdx.x;
  const int w = t >> 6, l = t & 63;
  const int c31 = l & 31, hi = l >> 5;
  // XCD-chunked swizzle: 768 blocks = 8 XCDs * 96; XCD k gets 6 consecutive bh
  const int blk = blockIdx.x;
  const int logical = (blk & 7) * 96 + (blk >> 3);
  const int bh = logical >> 4;
  const int qt = logical & 15;
  const int q0 = qt * 128 + w * 32;
  const int b = bh / HEADS, h = bh - b * HEADS;

  const ushort_t* Qp = Qd + (size_t)bh * SEQ * DH;
  const ushort_t* Kp = Kd + (size_t)bh * SEQ * DH;
  const ushort_t* Vp = Vt + (size_t)bh * DH * SEQ;

  // Q B-frags (resident): chunk c -> Q[q0 + (l&31)][16c + 8hi + 0..7] (pre-scaled by log2e)
  s16x8 qf[4];
  {
    const ushort_t* qp = Qp + (size_t)(q0 + c31) * DH + hi * 8;
#pragma unroll
    for (int c = 0; c < 4; ++c) qf[c] = *(const s16x8*)(qp + c * 16);
  }

  f32x16 oacc0 = {}, oacc1 = {};   // O^T d-frags 0..31 / 32..63; col q = l&31
  float psum = 0.f;

  // stage tile -> buf: wave w does segs {2w, 2w+1} for K and V (4 gload_lds16/wave)
#define STAGE(buf, tile)                                                           \
  {                                                                                \
    const int key0 = (tile) * KVT;                                                 \
    _Pragma("unroll")                                                              \
    for (int jj = 0; jj < 2; ++jj) {                                               \
      const int j = w * 2 + jj;                                                    \
      gload_lds16(Kp + (size_t)(key0 + l) * DH + j * 8,                            \
                  (char*)&Ks[buf][0] + j * 1024 + l * 16);                         \
      gload_lds16(Vp + (size_t)l * SEQ + key0 + j * 8,                             \
                  (char*)&Vs[buf][0] + j * 1024 + l * 16);                         \
    }                                                                              \
  }

#define COMPUTE(buf, st)                                                           \
  {                                                                                \
    const char* kb = (const char*)&Ks[buf][0];                                     \
    const char* vb = (const char*)&Vs[buf][0];                                     \
    s16x8 kf0 = *(const s16x8*)(kb + (0 + hi) * 1024 + ((st)*32 + c31) * 16);      \
    s16x8 kf1 = *(const s16x8*)(kb + (2 + hi) * 1024 + ((st)*32 + c31) * 16);      \
    s16x8 kf2 = *(const s16x8*)(kb + (4 + hi) * 1024 + ((st)*32 + c31) * 16);      \
    s16x8 kf3 = *(const s16x8*)(kb + (6 + hi) * 1024 + ((st)*32 + c31) * 16);      \
    s16x8 va00 = *(const s16x8*)(vb + ((st)*4 + 0 + hi) * 1024 + c31 * 16);        \
    s16x8 va01 = *(const s16x8*)(vb + ((st)*4 + 2 + hi) * 1024 + c31 * 16);        \
    s16x8 va10 = *(const s16x8*)(vb + ((st)*4 + 0 + hi) * 1024 + (32 + c31) * 16); \
    s16x8 va11 = *(const s16x8*)(vb + ((st)*4 + 2 + hi) * 1024 + (32 + c31) * 16); \
    f32x16 s0 = {}, s1 = {};                                                       \
    s0 = __builtin_amdgcn_mfma_f32_32x32x16_bf16(kf0, qf[0], s0, 0, 0, 0);         \
    s1 = __builtin_amdgcn_mfma_f32_32x32x16_bf16(kf1, qf[1], s1, 0, 0, 0);         \
    s0 = __builtin_amdgcn_mfma_f32_32x32x16_bf16(kf2, qf[2], s0, 0, 0, 0);         \
    s1 = __builtin_amdgcn_mfma_f32_32x32x16_bf16(kf3, qf[3], s1, 0, 0, 0);         \
    float pe[16];                                                                  \
    _Pragma("unroll")                                                              \
    for (int r2 = 0; r2 < 16; ++r2) {                                              \
      pe[r2] = __builtin_amdgcn_exp2f(s0[r2] + s1[r2]);                            \
      psum += pe[r2];                                                              \
    }                                                                              \
    u32x4 f0u = { pk2bf(pe[0],  pe[1]),  pk2bf(pe[2],  pe[3]),                     \
                  pk2bf(pe[4],  pe[5]),  pk2bf(pe[6],  pe[7]) };                   \
    u32x4 f1u = { pk2bf(pe[8],  pe[9]),  pk2bf(pe[10], pe[11]),                    \
                  pk2bf(pe[12], pe[13]), pk2bf(pe[14], pe[15]) };                  \
    const s16x8 pf0 = __builtin_bit_cast(s16x8, f0u);                              \
    const s16x8 pf1 = __builtin_bit_cast(s16x8, f1u);                              \
    oacc0 = __builtin_amdgcn_mfma_f32_32x32x16_bf16(va00, pf0, oacc0, 0, 0, 0);    \
    oacc0 = __builtin_amdgcn_mfma_f32_32x32x16_bf16(va01, pf1, oacc0, 0, 0, 0);    \
    oacc1 = __builtin_amdgcn_mfma_f32_32x32x16_bf16(va10, pf0, oacc1, 0, 0, 0);    \
    oacc1 = __builtin_amdgcn_mfma_f32_32x32x16_bf16(va11, pf1, oacc1, 0, 0, 0);    \
  }

  STAGE(0, 0);
  __syncthreads();

  for (int tt = 0; tt < NT; ++tt) {
    const int cur = tt & 1;
    if (tt + 1 < NT) STAGE(cur ^ 1, tt + 1);   // overlaps with compute below
    COMPUTE(cur, 0);
    COMPUTE(cur, 1);
    __syncthreads();   // drains vmcnt (stage) + lgkmcnt, releases both buffers
  }

  // row sum: lane l holds 16 of each 32-key group for q=l&31; lane l^32 has the rest
  float lt = psum + __shfl_xor(psum, 32);
  const float scale = 0.036084391824351615f / lt;   // (1/sqrt(768)) / l

  ushort_t* op = Oa + ((size_t)(b * SEQ + q0 + c31)) * EMB + h * DH;
#pragma unroll
  for (int f = 0; f < 2; ++f) {
    const f32x16& o = f ? oacc1 : oacc0;
#pragma unroll
    for (int rq = 0; rq < 4; ++rq) {
      const int dbase = f * 32 + 8 * rq + 4 * hi;    // d = dbase + (reg&3)
      uint2 u;
      u.x = pk2bf(o[rq*4+0] * scale, o[rq*4+1] * scale);
      u.y = pk2bf(o[rq*4+2] * scale, o[rq*4+3] * scale);
      *reinterpret_cast<uint2*>(op + dbase) = u;
    }
  }
}

// ---------------- host launch ----------------
extern "C" void kernel_launch(void* const* d_in, const int* in_sizes, int n_in,
                              void* d_out, int out_size, void* d_ws, size_t ws_size,
                              hipStream_t stream) {
  const float* x      = (const float*)d_in[0];
  const float* qkv_w  = (const float*)d_in[1];
  const float* qkv_b  = (const float*)d_in[2];
  const float* proj_w = (const float*)d_in[3];
  const float* proj_b = (const float*)d_in[4];
  float* out = (float*)d_out;

  ushort_t* xb    = (ushort_t*)d_ws;
  ushort_t* wqkv  = xb    + (size_t)MTOK*EMB;
  ushort_t* wproj = wqkv  + (size_t)NQKV*EMB;
  ushort_t* Qd    = wproj + (size_t)EMB*EMB;
  ushort_t* Kd    = Qd    + (size_t)MTOK*EMB;
  ushort_t* Vt    = Kd    + (size_t)MTOK*EMB;
  ushort_t* Oa    = Vt    + (size_t)MTOK*EMB;

  {
    int n4 = MTOK*EMB/4;
    cvt_bf16<<<(n4+255)/256, 256, 0, stream>>>(x, xb, n4);
  }
  {
    int n4 = NQKV*EMB/4;
    cvt_bf16<<<(n4+255)/256, 256, 0, stream>>>(qkv_w, wqkv, n4);
  }
  {
    int n4 = EMB*EMB/4;
    cvt_bf16<<<(n4+255)/256, 256, 0, stream>>>(proj_w, wproj, n4);
  }

  gemm_bt<1><<<dim3(NQKV/TN, MTOK/TM), 256, 0, stream>>>(
      xb, wqkv, qkv_b, nullptr, Qd, Kd, Vt, MTOK, NQKV, EMB);

  attn_fwd<<<768, 256, 0, stream>>>(Qd, Kd, Vt, Oa);

  gemm_bt<0><<<dim3(EMB/TN, MTOK/TM), 256, 0, stream>>>(
      Oa, wproj, proj_b, out, nullptr, nullptr, nullptr, MTOK, EMB, EMB);
}

// Round 6
// 179.435 us; speedup vs baseline: 1.5582x; 1.0028x over previous
//
#include <hip/hip_runtime.h>
#include <hip/hip_bf16.h>

typedef unsigned short ushort_t;
typedef __attribute__((ext_vector_type(8))) short s16x8;   // 8 bf16 (4 VGPRs)
typedef __attribute__((ext_vector_type(4))) float f32x4;
typedef __attribute__((ext_vector_type(16))) float f32x16;
typedef __attribute__((ext_vector_type(4))) unsigned int u32x4;

#define EMB 768
#define HEADS 12
#define DH 64
#define BATCH 4
#define SEQ 2048
#define MTOK (BATCH*SEQ)     // 8192
#define NQKV (3*EMB)         // 2304
#define LOG2E 1.44269504088896f

__device__ __forceinline__ ushort_t f2bf(float f) {
  unsigned u = __float_as_uint(f);
  u += 0x7fffu + ((u >> 16) & 1u);   // RNE; inputs have no NaN/Inf
  return (ushort_t)(u >> 16);
}
__device__ __forceinline__ unsigned pk2bf(float a, float b) {
  return (unsigned)f2bf(a) | ((unsigned)f2bf(b) << 16);
}
__device__ __forceinline__ unsigned cvtpk(float lo, float hi_) {
  unsigned d;
  asm("v_cvt_pk_bf16_f32 %0, %1, %2" : "=v"(d) : "v"(lo), "v"(hi_));
  return d;
}

__device__ __forceinline__ void gload_lds16(const void* g, void* l) {
  __builtin_amdgcn_global_load_lds(
      (const __attribute__((address_space(1))) unsigned*)g,
      (__attribute__((address_space(3))) unsigned*)l, 16, 0, 0);
}

// ---------------- fp32 -> bf16 convert (vectorized float4 -> 4x bf16) ----------------
__global__ void cvt_bf16(const float* __restrict__ in, ushort_t* __restrict__ out, int n4) {
  int i = blockIdx.x * blockDim.x + threadIdx.x;
  if (i >= n4) return;
  const float4 v = reinterpret_cast<const float4*>(in)[i];
  reinterpret_cast<uint2*>(out)[i] = make_uint2(pk2bf(v.x, v.y), pk2bf(v.z, v.w));
}

// ---------------- GEMM: C[M,N] = A[M,K] @ BT[N,K]^T + bias ----------------
// MODE 0: fp32 out to Cf.  MODE 1: scatter bf16 into Q[bh,n,d] (pre-scaled by log2e),
//         K[bh,n,d], Vt[bh,d,pos(n)] where pos(n) swaps bits 2<->3 of (n&31)
//         (matches the 32x32 MFMA C-layout key order so attn reads are contiguous).
#define TM 128
#define TN 128
#define BKG 64

template<int MODE>
__global__ __launch_bounds__(256, 2) void gemm_bt(
    const ushort_t* __restrict__ A, const ushort_t* __restrict__ BT,
    const float* __restrict__ bias, float* __restrict__ Cf,
    ushort_t* __restrict__ Qd, ushort_t* __restrict__ Kd, ushort_t* __restrict__ Vt,
    int M, int N, int K)
{
  __shared__ alignas(16) ushort_t As[TM*BKG];   // [128][64] bf16, XOR-swizzled (row&7)<<4
  __shared__ alignas(16) ushort_t Bs[TN*BKG];
  const int t = threadIdx.x;
  const int w = t >> 6, l = t & 63, g = l >> 4, r = l & 15;
  const int wr = w >> 1, wc = w & 1;                 // 2x2 wave grid, 64x64 per wave
  const int m0 = blockIdx.y * TM, n0 = blockIdx.x * TN;

  f32x4 acc[4][4] = {};

  for (int kt = 0; kt < K; kt += BKG) {
    // stage: linear LDS dest + inverse-swizzled global source (both-sides-or-neither)
#pragma unroll
    for (int p = 0; p < 4; ++p) {
      const int off = (t + p*256) * 16;              // byte in 16KB tile
      const int row = off >> 7;                      // 128B per row
      const int scb = (off & 127) ^ ((row & 7) << 4);
      gload_lds16(A  + (size_t)(m0+row)*K + kt + (scb>>1), (char*)As + off);
      gload_lds16(BT + (size_t)(n0+row)*K + kt + (scb>>1), (char*)Bs + off);
    }
    __syncthreads();   // compiler drains vmcnt(0) before s_barrier

    s16x8 fa[4][2], fb[4][2];
#pragma unroll
    for (int mi = 0; mi < 4; ++mi)
#pragma unroll
      for (int kk = 0; kk < 2; ++kk) {
        const int ra = wr*64 + mi*16 + r;
        fa[mi][kk] = *(const s16x8*)((const char*)As + ra*128 + ((g*16 + kk*64) ^ ((ra&7)<<4)));
        const int rb = wc*64 + mi*16 + r;
        fb[mi][kk] = *(const s16x8*)((const char*)Bs + rb*128 + ((g*16 + kk*64) ^ ((rb&7)<<4)));
      }
#pragma unroll
    for (int mi = 0; mi < 4; ++mi)
#pragma unroll
      for (int ni = 0; ni < 4; ++ni) {
        acc[mi][ni] = __builtin_amdgcn_mfma_f32_16x16x32_bf16(fa[mi][0], fb[ni][0], acc[mi][ni], 0,0,0);
        acc[mi][ni] = __builtin_amdgcn_mfma_f32_16x16x32_bf16(fa[mi][1], fb[ni][1], acc[mi][ni], 0,0,0);
      }
    __syncthreads();
  }

  // epilogue: C/D layout col = lane&15, row = (lane>>4)*4 + reg
#pragma unroll
  for (int mi = 0; mi < 4; ++mi)
#pragma unroll
    for (int ni = 0; ni < 4; ++ni) {
      const int col = n0 + wc*64 + ni*16 + r;
      const float bv = bias[col];
#pragma unroll
      for (int q = 0; q < 4; ++q) {
        const int rowg = m0 + wr*64 + mi*16 + g*4 + q;
        const float v = acc[mi][ni][q] + bv;
        if (MODE == 0) {
          Cf[(size_t)rowg * N + col] = v;
        } else {
          // col in [0,2304): (h:12, d:64, which:3), which fastest
          const int h = col / 192;
          const int rem = col - h*192;
          const int d = rem / 3;
          const int which = rem - d*3;
          const int bb = rowg >> 11, nn = rowg & 2047;
          if (which == 2) {
            // store V^T with bit2<->bit3-swapped column order within each 32-token block
            const int np = (nn & ~12) | ((nn & 4) << 1) | ((nn & 8) >> 1);
            Vt[((size_t)(bb*HEADS + h)*DH + d)*SEQ + np] = f2bf(v);
          } else {
            const size_t idx = ((size_t)(bb*HEADS + h)*SEQ + nn)*DH + d;
            if (which == 0) Qd[idx] = f2bf(v * LOG2E);   // fold log2(e) into Q
            else            Kd[idx] = f2bf(v);
          }
        }
      }
    }
}

// ---------------- flash attention: 64q/wave, every LDS read feeds 2 MFMAs -------------
// Block = 2 waves x 64 q rows = 128 q. K/V tiles (64 keys) double-buffered in LDS,
// fragment-order layout (all ds_read_b128 lane-contiguous, conflict-free).
// Softmax: fixed max=0 (exact), exp2-only, lane-local P (Vt bit2<->3 column permutation),
// P packed with v_cvt_pk_bf16_f32.
#define KVT 64
#define NT (SEQ/KVT)   // 32

__global__ __launch_bounds__(128, 2) void attn_fwd(
    const ushort_t* __restrict__ Qd, const ushort_t* __restrict__ Kd,
    const ushort_t* __restrict__ Vt, ushort_t* __restrict__ Oa)
{
  // K tile: seg = dchunk(0..7), byte = (seg*64 + key)*16   -> K[key][8seg..8seg+7]
  // V tile: seg = poschunk(0..7), byte = (seg*64 + d)*16   -> Vt[d][key0+8seg..+7]
  __shared__ alignas(16) ushort_t Ks[2][4096];
  __shared__ alignas(16) ushort_t Vs[2][4096];

  const int t = threadIdx.x;
  const int w = t >> 6, l = t & 63;
  const int c31 = l & 31, hi = l >> 5;
  // XCD-chunked swizzle: 768 blocks = 8 XCDs * 96; XCD k gets 6 consecutive bh
  const int blk = blockIdx.x;
  const int logical = (blk & 7) * 96 + (blk >> 3);
  const int bh = logical >> 4;
  const int qt = logical & 15;
  const int qb = qt * 128 + w * 64;     // this wave's 64 query rows
  const int b = bh / HEADS, h = bh - b * HEADS;

  const ushort_t* Qp = Qd + (size_t)bh * SEQ * DH;
  const ushort_t* Kp = Kd + (size_t)bh * SEQ * DH;
  const ushort_t* Vp = Vt + (size_t)bh * DH * SEQ;

  // Q B-frags: qf[j][c] = Q[qb + j*32 + (l&31)][16c + 8hi + 0..7]  (pre-scaled by log2e)
  s16x8 qf[2][4];
#pragma unroll
  for (int j = 0; j < 2; ++j) {
    const ushort_t* qp = Qp + (size_t)(qb + j*32 + c31) * DH + hi * 8;
#pragma unroll
    for (int c = 0; c < 4; ++c) qf[j][c] = *(const s16x8*)(qp + c * 16);
  }

  f32x16 oacc00 = {}, oacc01 = {};   // qfrag0: d 0..31 / 32..63
  f32x16 oacc10 = {}, oacc11 = {};   // qfrag1
  float psum0 = 0.f, psum1 = 0.f;

  // stage tile -> buf: 128 threads x 4 shots x 16B = 8KB each for K and V
#define STAGE(buf, tile)                                                           \
  {                                                                                \
    const int key0 = (tile) * KVT;                                                 \
    _Pragma("unroll")                                                              \
    for (int p = 0; p < 4; ++p) {                                                  \
      const int i = p * 128 + t;          /* 0..511 */                             \
      const int seg = i >> 6, idx = i & 63;                                        \
      gload_lds16(Kp + (size_t)(key0 + idx) * DH + seg * 8,                        \
                  (char*)&Ks[buf][0] + i * 16);                                    \
      gload_lds16(Vp + (size_t)idx * SEQ + key0 + seg * 8,                         \
                  (char*)&Vs[buf][0] + i * 16);                                    \
    }                                                                              \
  }

  // one 32-key group: 8 ds_read_b128 -> 16 MFMAs
#define KGROUP(buf, kg)                                                            \
  {                                                                                \
    const char* kb = (const char*)&Ks[buf][0];                                     \
    const char* vb = (const char*)&Vs[buf][0];                                     \
    s16x8 kf0 = *(const s16x8*)(kb + (((0 + hi) * 64) + (kg) * 32 + c31) * 16);    \
    s16x8 kf1 = *(const s16x8*)(kb + (((2 + hi) * 64) + (kg) * 32 + c31) * 16);    \
    s16x8 kf2 = *(const s16x8*)(kb + (((4 + hi) * 64) + (kg) * 32 + c31) * 16);    \
    s16x8 kf3 = *(const s16x8*)(kb + (((6 + hi) * 64) + (kg) * 32 + c31) * 16);    \
    f32x16 s0 = {}, s1 = {};                                                       \
    s0 = __builtin_amdgcn_mfma_f32_32x32x16_bf16(kf0, qf[0][0], s0, 0, 0, 0);      \
    s1 = __builtin_amdgcn_mfma_f32_32x32x16_bf16(kf0, qf[1][0], s1, 0, 0, 0);      \
    s0 = __builtin_amdgcn_mfma_f32_32x32x16_bf16(kf1, qf[0][1], s0, 0, 0, 0);      \
    s1 = __builtin_amdgcn_mfma_f32_32x32x16_bf16(kf1, qf[1][1], s1, 0, 0, 0);      \
    s0 = __builtin_amdgcn_mfma_f32_32x32x16_bf16(kf2, qf[0][2], s0, 0, 0, 0);      \
    s1 = __builtin_amdgcn_mfma_f32_32x32x16_bf16(kf2, qf[1][2], s1, 0, 0, 0);      \
    s0 = __builtin_amdgcn_mfma_f32_32x32x16_bf16(kf3, qf[0][3], s0, 0, 0, 0);      \
    s1 = __builtin_amdgcn_mfma_f32_32x32x16_bf16(kf3, qf[1][3], s1, 0, 0, 0);      \
    float pe0[16], pe1[16];                                                        \
    _Pragma("unroll")                                                              \
    for (int r2 = 0; r2 < 16; ++r2) {                                              \
      pe0[r2] = __builtin_amdgcn_exp2f(s0[r2]); psum0 += pe0[r2];                  \
      pe1[r2] = __builtin_amdgcn_exp2f(s1[r2]); psum1 += pe1[r2];                  \
    }                                                                              \
    u32x4 a0 = { cvtpk(pe0[0],  pe0[1]),  cvtpk(pe0[2],  pe0[3]),                  \
                 cvtpk(pe0[4],  pe0[5]),  cvtpk(pe0[6],  pe0[7]) };                \
    u32x4 a1 = { cvtpk(pe0[8],  pe0[9]),  cvtpk(pe0[10], pe0[11]),                 \
                 cvtpk(pe0[12], pe0[13]), cvtpk(pe0[14], pe0[15]) };               \
    u32x4 b0 = { cvtpk(pe1[0],  pe1[1]),  cvtpk(pe1[2],  pe1[3]),                  \
                 cvtpk(pe1[4],  pe1[5]),  cvtpk(pe1[6],  pe1[7]) };                \
    u32x4 b1 = { cvtpk(pe1[8],  pe1[9]),  cvtpk(pe1[10], pe1[11]),                 \
                 cvtpk(pe1[12], pe1[13]), cvtpk(pe1[14], pe1[15]) };               \
    const s16x8 pf00 = __builtin_bit_cast(s16x8, a0);                              \
    const s16x8 pf01 = __builtin_bit_cast(s16x8, a1);                              \
    const s16x8 pf10 = __builtin_bit_cast(s16x8, b0);                              \
    const s16x8 pf11 = __builtin_bit_cast(s16x8, b1);                              \
    s16x8 vaa0 = *(const s16x8*)(vb + ((4*(kg) + 0 + hi) * 64 + c31) * 16);        \
    s16x8 vaa1 = *(const s16x8*)(vb + ((4*(kg) + 0 + hi) * 64 + 32 + c31) * 16);   \
    s16x8 vab0 = *(const s16x8*)(vb + ((4*(kg) + 2 + hi) * 64 + c31) * 16);        \
    s16x8 vab1 = *(const s16x8*)(vb + ((4*(kg) + 2 + hi) * 64 + 32 + c31) * 16);   \
    oacc00 = __builtin_amdgcn_mfma_f32_32x32x16_bf16(vaa0, pf00, oacc00, 0, 0, 0); \
    oacc01 = __builtin_amdgcn_mfma_f32_32x32x16_bf16(vaa1, pf00, oacc01, 0, 0, 0); \
    oacc10 = __builtin_amdgcn_mfma_f32_32x32x16_bf16(vaa0, pf10, oacc10, 0, 0, 0); \
    oacc11 = __builtin_amdgcn_mfma_f32_32x32x16_bf16(vaa1, pf10, oacc11, 0, 0, 0); \
    oacc00 = __builtin_amdgcn_mfma_f32_32x32x16_bf16(vab0, pf01, oacc00, 0, 0, 0); \
    oacc01 = __builtin_amdgcn_mfma_f32_32x32x16_bf16(vab1, pf01, oacc01, 0, 0, 0); \
    oacc10 = __builtin_amdgcn_mfma_f32_32x32x16_bf16(vab0, pf11, oacc10, 0, 0, 0); \
    oacc11 = __builtin_amdgcn_mfma_f32_32x32x16_bf16(vab1, pf11, oacc11, 0, 0, 0); \
  }

  STAGE(0, 0);
  __syncthreads();

  for (int tt = 0; tt < NT; ++tt) {
    const int cur = tt & 1;
    if (tt + 1 < NT) STAGE(cur ^ 1, tt + 1);   // latency hides under compute below
    KGROUP(cur, 0);
    KGROUP(cur, 1);
    __syncthreads();   // drains vmcnt (stage) + lgkmcnt, releases both buffers
  }

  // row sums: lane holds 16 of each 32-key group; partner lane l^32 has the rest
  float lt0 = psum0 + __shfl_xor(psum0, 32);
  float lt1 = psum1 + __shfl_xor(psum1, 32);
  const float scale0 = 0.036084391824351615f / lt0;   // (1/sqrt(768)) / l
  const float scale1 = 0.036084391824351615f / lt1;

#pragma unroll
  for (int j = 0; j < 2; ++j) {
    const float sc = j ? scale1 : scale0;
    ushort_t* op = Oa + ((size_t)(b * SEQ + qb + j*32 + c31)) * EMB + h * DH;
#pragma unroll
    for (int f = 0; f < 2; ++f) {
      const f32x16& o = j ? (f ? oacc11 : oacc10) : (f ? oacc01 : oacc00);
#pragma unroll
      for (int rq = 0; rq < 4; ++rq) {
        const int dbase = f * 32 + 8 * rq + 4 * hi;    // d = dbase + (reg&3)
        uint2 u;
        u.x = pk2bf(o[rq*4+0] * sc, o[rq*4+1] * sc);
        u.y = pk2bf(o[rq*4+2] * sc, o[rq*4+3] * sc);
        *reinterpret_cast<uint2*>(op + dbase) = u;
      }
    }
  }
}

// ---------------- host launch ----------------
extern "C" void kernel_launch(void* const* d_in, const int* in_sizes, int n_in,
                              void* d_out, int out_size, void* d_ws, size_t ws_size,
                              hipStream_t stream) {
  const float* x      = (const float*)d_in[0];
  const float* qkv_w  = (const float*)d_in[1];
  const float* qkv_b  = (const float*)d_in[2];
  const float* proj_w = (const float*)d_in[3];
  const float* proj_b = (const float*)d_in[4];
  float* out = (float*)d_out;

  ushort_t* xb    = (ushort_t*)d_ws;
  ushort_t* wqkv  = xb    + (size_t)MTOK*EMB;
  ushort_t* wproj = wqkv  + (size_t)NQKV*EMB;
  ushort_t* Qd    = wproj + (size_t)EMB*EMB;
  ushort_t* Kd    = Qd    + (size_t)MTOK*EMB;
  ushort_t* Vt    = Kd    + (size_t)MTOK*EMB;
  ushort_t* Oa    = Vt    + (size_t)MTOK*EMB;

  {
    int n4 = MTOK*EMB/4;
    cvt_bf16<<<(n4+255)/256, 256, 0, stream>>>(x, xb, n4);
  }
  {
    int n4 = NQKV*EMB/4;
    cvt_bf16<<<(n4+255)/256, 256, 0, stream>>>(qkv_w, wqkv, n4);
  }
  {
    int n4 = EMB*EMB/4;
    cvt_bf16<<<(n4+255)/256, 256, 0, stream>>>(proj_w, wproj, n4);
  }

  gemm_bt<1><<<dim3(NQKV/TN, MTOK/TM), 256, 0, stream>>>(
      xb, wqkv, qkv_b, nullptr, Qd, Kd, Vt, MTOK, NQKV, EMB);

  attn_fwd<<<768, 128, 0, stream>>>(Qd, Kd, Vt, Oa);

  gemm_bt<0><<<dim3(EMB/TN, MTOK/TM), 256, 0, stream>>>(
      Oa, wproj, proj_b, out, nullptr, nullptr, nullptr, MTOK, EMB, EMB);
}